// Round 8
// baseline (13.801 us; speedup 1.0000x reference)
//
#include <hip/hip_runtime.h>

#define NUM_CLASSES 80
#define OUT_W 13
#define OUT_H 13
#define HW (OUT_W * OUT_H)   // 169
#define NA 5
#define NB 20
#define NBATCH 512
#define BPB 2                 // batches per block
#define NBLK (NBATCH / BPB)   // 256 blocks = 1 per CU, single scheduling wave

// Kernel 1: one block per 2 batches (independent interleaved latency chains).
// Each of the 4 waves stores its weighted partial to partials[blk*4+wave].
__global__ __launch_bounds__(256)
void yolo_loss_main(const float* __restrict__ bbox_pred,
                    const float* __restrict__ iou_pred,
                    const float* __restrict__ prob_pred,
                    const float* __restrict__ bbox_gt,
                    const int*   __restrict__ cls_gt,
                    const float* __restrict__ anchors,
                    double* __restrict__ partials)
{
    const int blk = blockIdx.x;
    const int b0  = blk * BPB;          // batches b0, b0+1
    const int tid = threadIdx.x;

    __shared__ int   s_slot[BPB * NB];     // [j*20+n] cell*NA + best
    __shared__ int   s_cls[BPB * NB];
    __shared__ float s_tgt[BPB * NB][4];   // tx, ty, sqrt(gw), sqrt(gh)
    __shared__ int   s_win[BPB * NB];
    __shared__ int   s_dup[BPB * NB];

    // ---- Issue all independent first-touch loads up front (tid<40: wave 0) ----
    float gx = 0.f, gy = 0.f, gw = 0.f, gh = 0.f;
    float a0w=0.f,a0h=0.f,a1w=0.f,a1h=0.f,a2w=0.f,a2h=0.f,a3w=0.f,a3h=0.f,a4w=0.f,a4h=0.f;
    int   my_cls = 0;
    if (tid < BPB * NB) {
        const int j = tid / NB, n = tid - j * NB;
        const float4 g4 = *(const float4*)(bbox_gt + ((size_t)(b0 + j) * NB + n) * 4);
        gx = g4.x; gy = g4.y; gw = g4.z; gh = g4.w;
        my_cls = cls_gt[(size_t)(b0 + j) * NB + n];
        a0w = anchors[0]; a0h = anchors[1];
        a1w = anchors[2]; a1h = anchors[3];
        a2w = anchors[4]; a2h = anchors[5];
        a3w = anchors[6]; a3h = anchors[7];
        a4w = anchors[8]; a4h = anchors[9];
    }

    // ---- Phase 2: dense IoU term 0.25*p^2 for both batches, all loads issue ----
    double acc_iou = 0.0;
    double w = 0.0;
    const float* ip0 = iou_pred + (size_t)b0 * HW * NA;
    const float* ip1 = ip0 + HW * NA;
    #pragma unroll
    for (int k = 0; k < 4; ++k) {
        const int i = tid + 256 * k;
        const float p = (i < HW * NA) ? ip0[i] : 0.0f;
        acc_iou += (double)(0.25f * p * p);
    }
    #pragma unroll
    for (int k = 0; k < 4; ++k) {
        const int i = tid + 256 * k;
        const float p = (i < HW * NA) ? ip1[i] : 0.0f;
        acc_iou += (double)(0.25f * p * p);
    }

    // ---- Phase 1: per-GT target computation (tid<40, wave 0, registers) ----
    if (tid < BPB * NB) {
        const float rg = gw / gh;
        int best = 0;
        float bd = fabsf(a0w / a0h - rg);
        float d;
        d = fabsf(a1w / a1h - rg); if (d < bd) { bd = d; best = 1; }
        d = fabsf(a2w / a2h - rg); if (d < bd) { bd = d; best = 2; }
        d = fabsf(a3w / a3h - rg); if (d < bd) { bd = d; best = 3; }
        d = fabsf(a4w / a4h - rg); if (d < bd) { bd = d; best = 4; }  // strict <: argmin
        const float cx = gx * (float)OUT_W;
        const float cy = gy * (float)OUT_H;
        const float fx = floorf(cx), fy = floorf(cy);
        const int cell = (int)(fy * (float)OUT_W + fx);
        s_slot[tid]   = cell * NA + best;
        s_cls[tid]    = my_cls;
        s_tgt[tid][0] = cx - fx;
        s_tgt[tid][1] = cy - fy;
        s_tgt[tid][2] = sqrtf(gw);
        s_tgt[tid][3] = sqrtf(gh);
    }
    // win/dup: written AND read by wave 0 only (tid<40) -> intra-wave order suffices.
    __builtin_amdgcn_wave_barrier();
    if (tid < BPB * NB) {
        const int j = tid / NB;
        const int base = j * NB;
        const int slot = s_slot[tid];
        int win = 1;
        for (int m = tid + 1; m < base + NB; ++m)
            if (s_slot[m] == slot) { win = 0; break; }   // later write overwrites
        s_win[tid] = win;
        int dup = 0;
        for (int m = base; m < tid; ++m)
            if (s_slot[m] == slot && s_cls[m] == s_cls[tid]) { dup = 1; break; }
        s_dup[tid] = dup;
    }
    __syncthreads();   // publish s_* to all waves

    const double N1 = (double)NBATCH * HW * NA * 4;
    const double N2 = (double)NBATCH * HW * NA;
    const double N3 = (double)NBATCH * HW * NA * NUM_CLASSES;

    // ---- Phase 3: per-winner bbox + IoU corrections (tid<40) ----
    if (tid < BPB * NB && s_win[tid]) {
        const int j = tid / NB;
        const int slot = s_slot[tid];
        const int a = slot % NA;
        float aw = a0w, ah = a0h;
        if (a == 1) { aw = a1w; ah = a1h; }
        if (a == 2) { aw = a2w; ah = a2h; }
        if (a == 3) { aw = a3w; ah = a3h; }
        if (a == 4) { aw = a4w; ah = a4h; }
        const float4 pp = *(const float4*)(bbox_pred + (((size_t)(b0 + j) * HW * NA) + slot) * 4);
        const float bp0 = pp.x, bp1 = pp.y;
        const float bp2 = sqrtf(pp.z * aw);
        const float bp3 = sqrtf(pp.w * ah);
        const float t0 = s_tgt[tid][0], t1 = s_tgt[tid][1];
        const float t2 = s_tgt[tid][2], t3 = s_tgt[tid][3];

        const float d0 = bp0 - t0, d1 = bp1 - t1, d2 = bp2 - t2, d3 = bp3 - t3;
        w += 5.0 / N1 * ((double)(d0 * d0) + (double)(d1 * d1)
                       + (double)(d2 * d2) + (double)(d3 * d3));

        const float area1 = bp2 * bp3, area2 = t2 * t3;
        float iw = fminf(bp0 + bp2, t0 + t2) - fmaxf(bp0, t0);
        float ih = fminf(bp1 + bp3, t1 + t3) - fmaxf(bp1, t1);
        iw = fmaxf(iw, 0.0f);
        ih = fmaxf(ih, 0.0f);
        const float inter = iw * ih;
        const float iou = inter / (area1 + area2 - inter);

        const float p = (j == 0 ? ip0 : ip1)[slot];
        acc_iou += (double)((p - iou) * (p - iou) - 0.25f * p * p);
    }

    // ---- Phase 4: cls term, 2 batches x 400 quad-items = 800, 4 masked gathers ----
    const float* prp0 = prob_pred + (size_t)b0 * HW * NA * NUM_CLASSES;
    double acc_cls = 0.0;
    #pragma unroll
    for (int k = 0; k < 4; ++k) {
        const int idx = tid + 256 * k;                  // < 800
        if (idx < BPB * NB * (NUM_CLASSES / 4)) {
            const int j = idx / (NB * (NUM_CLASSES / 4));
            const int r = idx - j * (NB * (NUM_CLASSES / 4));
            const int n = r / (NUM_CLASSES / 4), q = r - n * (NUM_CLASSES / 4);
            if (s_win[j * NB + n]) {
                const float* base = prp0 + (size_t)j * HW * NA * NUM_CLASSES;
                const float4 p4 = *(const float4*)(base + (size_t)s_slot[j * NB + n] * NUM_CLASSES + q * 4);
                acc_cls += (double)(p4.x * p4.x) + (double)(p4.y * p4.y)
                         + (double)(p4.z * p4.z) + (double)(p4.w * p4.w);
            }
        }
    }
    // Per unique (slot, class): (p-1)^2 - p^2 = 1 - 2p
    if (tid < BPB * NB && !s_dup[tid]) {
        const int j = tid / NB;
        const float* base = prp0 + (size_t)j * HW * NA * NUM_CLASSES;
        const float p = base[(size_t)s_slot[tid] * NUM_CLASSES + s_cls[tid]];
        acc_cls += (double)(1.0f - 2.0f * p);
    }

    // ---- Fold weights per-thread, per-wave shuffle reduce, 4 plain stores ----
    w += acc_iou / N2 + acc_cls / N3;
    for (int off = 32; off > 0; off >>= 1)
        w += __shfl_down(w, off);
    const int wave = tid >> 6, lane = tid & 63;
    if (lane == 0)
        partials[(size_t)blk * 4 + wave] = w;   // no barrier, no LDS
}

// Kernel 2: one wave sums 1024 doubles and writes the scalar loss.
__global__ __launch_bounds__(64)
void yolo_loss_final(const double* __restrict__ partials,
                     float* __restrict__ out)
{
    const int tid = threadIdx.x;
    double s = 0.0;
    #pragma unroll
    for (int k = 0; k < 16; ++k)         // 16 independent loads, one wait
        s += partials[tid + 64 * k];
    for (int off = 32; off > 0; off >>= 1)
        s += __shfl_down(s, off);
    if (tid == 0) out[0] = (float)s;
}

extern "C" void kernel_launch(void* const* d_in, const int* in_sizes, int n_in,
                              void* d_out, int out_size, void* d_ws, size_t ws_size,
                              hipStream_t stream)
{
    const float* bbox_pred = (const float*)d_in[0];
    const float* iou_pred  = (const float*)d_in[1];
    const float* prob_pred = (const float*)d_in[2];
    const float* bbox_gt   = (const float*)d_in[3];
    const int*   cls_gt    = (const int*)d_in[4];
    const float* anchors   = (const float*)d_in[5];
    float* out = (float*)d_out;
    double* partials = (double*)d_ws;   // 256*4 doubles = 8 KiB

    yolo_loss_main<<<NBLK, 256, 0, stream>>>(bbox_pred, iou_pred, prob_pred,
                                             bbox_gt, cls_gt, anchors, partials);
    yolo_loss_final<<<1, 64, 0, stream>>>(partials, out);
}

// Round 9
// 13.337 us; speedup vs baseline: 1.0348x; 1.0348x over previous
//
#include <hip/hip_runtime.h>

#define NUM_CLASSES 80
#define OUT_W 13
#define OUT_H 13
#define HW (OUT_W * OUT_H)   // 169
#define NA 5
#define NB 20
#define NBATCH 512

// Kernel 1: one block per batch. Each of the 4 waves stores its own weighted
// partial to partials[b*4+wave] (no epilogue barrier, no LDS reduce).
// [R8 lesson: 1 batch/block (512 blocks) beats 2 batches/block (256 blocks) —
//  per-block critical path dominates over block-scheduling tail.]
__global__ __launch_bounds__(256)
void yolo_loss_main(const float* __restrict__ bbox_pred,
                    const float* __restrict__ iou_pred,
                    const float* __restrict__ prob_pred,
                    const float* __restrict__ bbox_gt,
                    const int*   __restrict__ cls_gt,
                    const float* __restrict__ anchors,
                    double* __restrict__ partials)
{
    const int b   = blockIdx.x;
    const int tid = threadIdx.x;

    __shared__ int   s_slot[NB];      // cell*NA + best
    __shared__ int   s_cls[NB];
    __shared__ float s_tgt[NB][4];    // tx, ty, sqrt(gw), sqrt(gh)
    __shared__ int   s_win[NB];       // 1 if this n is the last writer to its slot
    __shared__ int   s_dup[NB];       // 1 if an earlier m has same (slot, class)

    // ---- Issue all independent first-touch loads up front (tid<NB: wave 0) ----
    float gx = 0.f, gy = 0.f, gw = 0.f, gh = 0.f;
    float a0w=0.f,a0h=0.f,a1w=0.f,a1h=0.f,a2w=0.f,a2h=0.f,a3w=0.f,a3h=0.f,a4w=0.f,a4h=0.f;
    int   my_cls = 0;
    if (tid < NB) {
        const float4 g4 = *(const float4*)(bbox_gt + ((size_t)b * NB + tid) * 4);
        gx = g4.x; gy = g4.y; gw = g4.z; gh = g4.w;
        my_cls = cls_gt[(size_t)b * NB + tid];
        a0w = anchors[0]; a0h = anchors[1];
        a1w = anchors[2]; a1h = anchors[3];
        a2w = anchors[4]; a2h = anchors[5];
        a3w = anchors[6]; a3h = anchors[7];
        a4w = anchors[8]; a4h = anchors[9];
    }

    // ---- Phase 2 (independent): dense IoU term 0.25*p^2 ----
    // 4 compile-time-unrolled masked loads: all issue, single wait.
    double acc_iou = 0.0;
    double w = 0.0;
    const float* ip = iou_pred + (size_t)b * HW * NA;
    #pragma unroll
    for (int k = 0; k < 4; ++k) {
        const int i = tid + 256 * k;
        const float p = (i < HW * NA) ? ip[i] : 0.0f;
        acc_iou += (double)(0.25f * p * p);
    }

    // ---- Phase 1: per-GT target computation (wave 0, registers) ----
    if (tid < NB) {
        const float rg = gw / gh;
        int best = 0;
        float bd = fabsf(a0w / a0h - rg);
        float d;
        d = fabsf(a1w / a1h - rg); if (d < bd) { bd = d; best = 1; }
        d = fabsf(a2w / a2h - rg); if (d < bd) { bd = d; best = 2; }
        d = fabsf(a3w / a3h - rg); if (d < bd) { bd = d; best = 3; }
        d = fabsf(a4w / a4h - rg); if (d < bd) { bd = d; best = 4; }  // strict <: argmin
        const float cx = gx * (float)OUT_W;
        const float cy = gy * (float)OUT_H;
        const float fx = floorf(cx), fy = floorf(cy);
        const int cell = (int)(fy * (float)OUT_W + fx);
        s_slot[tid]   = cell * NA + best;
        s_cls[tid]    = my_cls;
        s_tgt[tid][0] = cx - fx;
        s_tgt[tid][1] = cy - fy;
        s_tgt[tid][2] = sqrtf(gw);
        s_tgt[tid][3] = sqrtf(gh);
    }
    // win/dup: written AND read by wave 0 only -> intra-wave LDS order suffices.
    __builtin_amdgcn_wave_barrier();   // compiler ordering fence (no-op at runtime)
    if (tid < NB) {
        const int n = tid, slot = s_slot[n];
        int win = 1;
        for (int m = n + 1; m < NB; ++m)
            if (s_slot[m] == slot) { win = 0; break; }   // later write overwrites
        s_win[n] = win;
        int dup = 0;
        for (int m = 0; m < n; ++m)
            if (s_slot[m] == slot && s_cls[m] == s_cls[n]) { dup = 1; break; }
        s_dup[n] = dup;
    }
    __syncthreads();   // publish s_* to all waves

    const double N1 = (double)NBATCH * HW * NA * 4;
    const double N2 = (double)NBATCH * HW * NA;
    const double N3 = (double)NBATCH * HW * NA * NUM_CLASSES;

    // ---- Phase 3: per-winner bbox + IoU corrections (wave 0) ----
    if (tid < NB && s_win[tid]) {
        const int n = tid;
        const int slot = s_slot[n];
        const int a = slot % NA;
        float aw = a0w, ah = a0h;
        if (a == 1) { aw = a1w; ah = a1h; }
        if (a == 2) { aw = a2w; ah = a2h; }
        if (a == 3) { aw = a3w; ah = a3h; }
        if (a == 4) { aw = a4w; ah = a4h; }
        const float4 pp = *(const float4*)(bbox_pred + (((size_t)b * HW * NA) + slot) * 4);
        const float bp0 = pp.x, bp1 = pp.y;
        const float bp2 = sqrtf(pp.z * aw);
        const float bp3 = sqrtf(pp.w * ah);
        const float t0 = s_tgt[n][0], t1 = s_tgt[n][1];
        const float t2 = s_tgt[n][2], t3 = s_tgt[n][3];

        const float d0 = bp0 - t0, d1 = bp1 - t1, d2 = bp2 - t2, d3 = bp3 - t3;
        w += 5.0 / N1 * ((double)(d0 * d0) + (double)(d1 * d1)
                       + (double)(d2 * d2) + (double)(d3 * d3));

        const float area1 = bp2 * bp3, area2 = t2 * t3;
        float iw = fminf(bp0 + bp2, t0 + t2) - fmaxf(bp0, t0);
        float ih = fminf(bp1 + bp3, t1 + t3) - fmaxf(bp1, t1);
        iw = fmaxf(iw, 0.0f);
        ih = fmaxf(ih, 0.0f);
        const float inter = iw * ih;
        const float iou = inter / (area1 + area2 - inter);

        const float p = ip[slot];
        acc_iou += (double)((p - iou) * (p - iou) - 0.25f * p * p);
    }

    // ---- Phase 4: cls term, 2 unrolled masked float4 gathers ----
    const float* prp = prob_pred + (size_t)b * HW * NA * NUM_CLASSES;
    double acc_cls = 0.0;
    #pragma unroll
    for (int k = 0; k < 2; ++k) {
        const int idx = tid + 256 * k;            // < NB*20 = 400
        if (idx < NB * (NUM_CLASSES / 4)) {
            const int n = idx / (NUM_CLASSES / 4), q = idx - n * (NUM_CLASSES / 4);
            if (s_win[n]) {
                const float4 p4 = *(const float4*)(prp + (size_t)s_slot[n] * NUM_CLASSES + q * 4);
                acc_cls += (double)(p4.x * p4.x) + (double)(p4.y * p4.y)
                         + (double)(p4.z * p4.z) + (double)(p4.w * p4.w);
            }
        }
    }
    // Per unique (slot, class): (p-1)^2 - p^2 = 1 - 2p
    if (tid < NB && !s_dup[tid]) {
        const float p = prp[(size_t)s_slot[tid] * NUM_CLASSES + s_cls[tid]];
        acc_cls += (double)(1.0f - 2.0f * p);
    }

    // ---- Fold weights per-thread, per-wave shuffle reduce, 4 plain stores ----
    w += acc_iou / N2 + acc_cls / N3;
    for (int off = 32; off > 0; off >>= 1)
        w += __shfl_down(w, off);
    const int wave = tid >> 6, lane = tid & 63;
    if (lane == 0)
        partials[(size_t)b * 4 + wave] = w;   // no barrier, no LDS
}

// Kernel 2: one wave sums 2048 doubles and writes the scalar loss.
__global__ __launch_bounds__(64)
void yolo_loss_final(const double* __restrict__ partials,
                     float* __restrict__ out)
{
    const int tid = threadIdx.x;
    double s = 0.0;
    #pragma unroll
    for (int k = 0; k < 32; ++k)         // 32 independent loads, one wait
        s += partials[tid + 64 * k];
    for (int off = 32; off > 0; off >>= 1)
        s += __shfl_down(s, off);
    if (tid == 0) out[0] = (float)s;
}

extern "C" void kernel_launch(void* const* d_in, const int* in_sizes, int n_in,
                              void* d_out, int out_size, void* d_ws, size_t ws_size,
                              hipStream_t stream)
{
    const float* bbox_pred = (const float*)d_in[0];
    const float* iou_pred  = (const float*)d_in[1];
    const float* prob_pred = (const float*)d_in[2];
    const float* bbox_gt   = (const float*)d_in[3];
    const int*   cls_gt    = (const int*)d_in[4];
    const float* anchors   = (const float*)d_in[5];
    float* out = (float*)d_out;
    double* partials = (double*)d_ws;   // 512*4 doubles = 16 KiB

    yolo_loss_main<<<NBATCH, 256, 0, stream>>>(bbox_pred, iou_pred, prob_pred,
                                               bbox_gt, cls_gt, anchors, partials);
    yolo_loss_final<<<1, 64, 0, stream>>>(partials, out);
}